// Round 3
// baseline (12814.874 us; speedup 1.0000x reference)
//
#include <hip/hip_runtime.h>
#include <stdint.h>
#include <stddef.h>

// Problem constants (from reference): B=256, T=512, D=512, H=256
#define NBATCH 256
#define NTIME  512
#define NDIM   512
#define NHID   256

using s16x8 = __attribute__((ext_vector_type(8))) short;   // 8 bf16 bit patterns
using f32x4 = __attribute__((ext_vector_type(4))) float;

#define MFMA16 __builtin_amdgcn_mfma_f32_16x16x32_bf16

// ---------------- persistent device-global state ----------------
// h-state double buffered, split-bf16 (hi+lo) planes. Fully rewritten before
// each read in every launch -> replay-safe.
__device__ alignas(16) unsigned short g_h_hi[4][2][NBATCH][NHID];
__device__ alignas(16) unsigned short g_h_lo[4][2][NBATCH][NHID];
// y1 ring (engine 3 -> engines 0,1), depth 4
__device__ alignas(16) unsigned short g_y1_hi[4][NBATCH][NHID];
__device__ alignas(16) unsigned short g_y1_lo[4][NBATCH][NHID];
// s2x2 (engine2 -> engine3) single slot; s1y1 (engine0 -> engine1) ring 2
__device__ float g_s2[NBATCH][NHID];
__device__ float g_s1[2][NBATCH][NHID];
// sync state. All protocols leave flags exactly as they found them (barrier
// values window-matched; handshake flags return to 0) -> graph-replay-safe.
__device__ unsigned g_bar[16][16];        // [group][slot i] window barrier
__device__ unsigned g_s2f[4][16];         // [q][i]   0=empty, t+1=full
__device__ unsigned g_s1f[2][4][16];      // [slot][q][i]
__device__ unsigned g_y1f[2][4][4][16];   // [consumer 0/1][q][slot][i]

__device__ __forceinline__ unsigned short f2bf(float f) {
  union { float f; unsigned u; } c; c.f = f;
  unsigned u = c.u;
  u = (u + 0x7FFFu + ((u >> 16) & 1u)) >> 16;   // round-to-nearest-even bf16
  return (unsigned short)u;
}
__device__ __forceinline__ float bf2f(unsigned short h) {
  union { float f; unsigned u; } c; c.u = ((unsigned)h) << 16; return c.f;
}
// Relaxed flag ops; ordering is done ONCE per edge with explicit agent fences
// (keeps cache-maintenance out of the spin-loop body).
__device__ __forceinline__ unsigned flag_ld(const unsigned* p) {
  return __hip_atomic_load(p, __ATOMIC_RELAXED, __HIP_MEMORY_SCOPE_AGENT);
}
__device__ __forceinline__ void flag_st(unsigned* p, unsigned v) {
  __hip_atomic_store(p, v, __ATOMIC_RELAXED, __HIP_MEMORY_SCOPE_AGENT);
}
__device__ __forceinline__ void fence_acq() {
  __builtin_amdgcn_fence(__ATOMIC_ACQUIRE, "agent");
}
__device__ __forceinline__ void fence_rel() {
  __builtin_amdgcn_fence(__ATOMIC_RELEASE, "agent");
}
// bounded spin: on cap-trip set shared dead flag and fall through (wrong-fast
// instead of hang; all subsequent spins skip, flag *stores* still happen).
__device__ __forceinline__ void spin2(const unsigned* p, unsigned a, unsigned b, int* sdead) {
  if (*sdead) return;
  long c = 0;
  for (;;) {
    unsigned v = flag_ld(p);
    if (v == a || v == b) return;
    if (++c > (1L << 21)) { *sdead = 1; return; }
    __builtin_amdgcn_s_sleep(1);
  }
}

__launch_bounds__(256, 1)
__global__ void revgru(const float* __restrict__ x,
                       const float* __restrict__ Wih,
                       const float* __restrict__ Whh,
                       const float* __restrict__ bih,
                       const float* __restrict__ bhh,
                       const float* __restrict__ Wout,
                       const float* __restrict__ bout,
                       float* __restrict__ out)
{
  // STATIC LDS (compile-time validated; no runtime attribute negotiation).
  // 114688 B forces exactly 1 wg/CU -> 256 wgs co-resident on 256 CUs,
  // which is what makes the spin protocols deadlock-free by construction.
  __shared__ unsigned short lds[57344];
  __shared__ int s_dead;
  int* sdp = (int*)&s_dead;

  // LDS layout (ushort units): weight slices as split-bf16 planes.
  // [48][256] gate-weight slices (rows = {r,z,n} x 16 h-cols), [16][256] Wout.
  unsigned short* L_whh_hi = lds;
  unsigned short* L_whh_lo = lds + 12288;
  unsigned short* L_wih_hi = lds + 24576;
  unsigned short* L_wih_lo = lds + 36864;
  unsigned short* L_wo_hi  = lds + 49152;
  unsigned short* L_wo_lo  = lds + 53248;   // end = 57344 shorts = 114688 B

  const int tid = threadIdx.x;
  const int bid = blockIdx.x;
  // decode (engine s, quarter q, h-slice i). Bits of bid: i=bits3-6, q=bits1-2,
  // s = (bit0<<1)|bit7 — bijective over 256 blocks. Under round-robin
  // block->XCD dispatch (XCD = bid%8 = bits0-2) all 16 i-wgs of a given (s,q)
  // share one XCD -> the x2 slice and h-state stay in that XCD's L2.
  // Correctness does not depend on placement.
  const int i    = (bid >> 3) & 15;
  const int q    = (bid >> 1) & 3;
  const int s    = ((bid & 1) << 1) | (bid >> 7);
  const int grp  = s * 4 + q;               // 0..15
  const int w    = tid >> 6;                // wave = M-tile
  const int l    = tid & 63;
  const int lrow = l & 15;                  // matrix-dim index of this lane
  const int kg   = l >> 4;                  // k-group
  const int rowbase = 64 * q + 16 * w;      // this wave's 16 batch rows
  const int hcol = 16 * i + lrow;           // this lane's h/output column

  if (tid == 0) s_dead = 0;

  // ---- stage weight slices into LDS (convert fp32 -> bf16 hi/lo), swizzled.
  // 16B-granule XOR swizzle: granule g stored at g ^ (c&7) within row c.
  // (c*512B ≡ bank0 mod 32 banks — the XOR spreads the 8 c-values of a
  // 16-lane read group over all 32 banks: ≤2-way aliasing, free per m136.)
  for (int it = tid; it < 48 * 256; it += 256) {
    const int c = it >> 8, k = it & 255;
    const int gr = ((c >> 4) * NHID) + 16 * i + (c & 15);  // gate*H + hcol
    const int pos = (c << 8) | ((((k >> 3) ^ (c & 7)) << 3) | (k & 7));
    float v1 = Whh[((size_t)s * 3 * NHID + gr) * NHID + k];
    unsigned short h1 = f2bf(v1);
    L_whh_hi[pos] = h1; L_whh_lo[pos] = f2bf(v1 - bf2f(h1));
    float v2 = Wih[((size_t)s * 3 * NHID + gr) * NHID + k];
    unsigned short h2 = f2bf(v2);
    L_wih_hi[pos] = h2; L_wih_lo[pos] = f2bf(v2 - bf2f(h2));
  }
  for (int it = tid; it < 16 * 256; it += 256) {
    const int c = it >> 8, k = it & 255;
    const int oc = 16 * i + c;
    const int pos = (c << 8) | ((((k >> 3) ^ (c & 7)) << 3) | (k & 7));
    float v = Wout[((size_t)s * NHID + oc) * NHID + k];
    unsigned short h = f2bf(v);
    L_wo_hi[pos] = h; L_wo_lo[pos] = f2bf(v - bf2f(h));
  }
  // per-lane biases (fixed all run). n-gate keeps bih/bhh separate (r scales bhh_n).
  const float b_r  = bih[s * 3 * NHID + 0 * NHID + hcol] + bhh[s * 3 * NHID + 0 * NHID + hcol];
  const float b_z  = bih[s * 3 * NHID + 1 * NHID + hcol] + bhh[s * 3 * NHID + 1 * NHID + hcol];
  const float bi_n = bih[s * 3 * NHID + 2 * NHID + hcol];
  const float bh_n = bhh[s * 3 * NHID + 2 * NHID + hcol];
  const float b_o  = bout[s * NHID + hcol];
  const float ESC  = (float)(5.0 * 0.636);  // CLAMP * 0.636

  // zero h(t=-1): buffer index 1 (t=0 reads pb=1)
  for (int it = tid; it < 64 * 16; it += 256) {
    const int r = 64 * q + (it >> 4), c = 16 * i + (it & 15);
    g_h_hi[s][1][r][c] = 0; g_h_lo[s][1][r][c] = 0;
  }

  // Window barrier across the 16 wgs of this engine-group. A wg arriving at
  // barrier n may observe peers already at n+1 (max skew 1: passing barrier n
  // requires all peers to have PUBLISHED n, so no wg publishes n+2 before
  // every peer published n+1... i.e. values seen while spinning ∈ {n, n+1}).
  // Single release fence before publish, single acquire fence after the spin.
#define ENG_BARRIER(nval) do {                                              \
    unsigned _n = (unsigned)(nval);                                         \
    __syncthreads();                                                        \
    if (tid == 0) { fence_rel(); flag_st(&g_bar[grp][i], _n); }             \
    if (tid < 16) spin2(&g_bar[grp][tid], _n, _n + 1u, sdp);                \
    if (tid == 0) fence_acq();                                              \
    __syncthreads();                                                        \
  } while (0)

  ENG_BARRIER(1);   // h zeros + LDS weights ready within the group

  for (int t = 0; t < NTIME; ++t) {
    const int pb = (t + 1) & 1, cb = t & 1;
    const int ysl = t & 3;
    const int arow = rowbase + lrow;

    // consumers of y1 wait for all 16 producer slices of their quarter
    if (s < 2) {
      if (tid < 16) spin2(&g_y1f[s][q][ysl][tid], (unsigned)(t + 1), (unsigned)(t + 1), sdp);
      if (tid == 0) fence_acq();
      __syncthreads();
    }

    // ===== gate matmuls: agh = h_prev @ Whh_slice^T ; agx = inp @ Wih_slice^T
    f32x4 agx[3], agh[3];
#pragma unroll
    for (int n2 = 0; n2 < 3; ++n2) {
      agx[n2] = (f32x4){0.f, 0.f, 0.f, 0.f};
      agh[n2] = (f32x4){0.f, 0.f, 0.f, 0.f};
    }
    const unsigned short* __restrict__ hp_hi = &g_h_hi[s][pb][0][0];
    const unsigned short* __restrict__ hp_lo = &g_h_lo[s][pb][0][0];
    for (int kk = 0; kk < 8; ++kk) {
      const int k0 = kk * 32 + kg * 8;
      s16x8 ah_hi = *(const s16x8*)&hp_hi[arow * NHID + k0];
      s16x8 ah_lo = *(const s16x8*)&hp_lo[arow * NHID + k0];
      s16x8 ax_hi, ax_lo;
      if (s >= 2) {   // input = x2 (fp32 from HBM/L2), split on the fly
        const float* xp = &x[((size_t)arow * NTIME + t) * NDIM + NHID + k0];
        f32x4 xa = *(const f32x4*)xp;
        f32x4 xb = *(const f32x4*)(xp + 4);
#pragma unroll
        for (int e = 0; e < 8; ++e) {
          float v = (e < 4) ? xa[e] : xb[e - 4];
          unsigned short hh = f2bf(v);
          ax_hi[e] = (short)hh;
          ax_lo[e] = (short)f2bf(v - bf2f(hh));
        }
      } else {        // input = y1 (pre-split by engine 3)
        ax_hi = *(const s16x8*)&g_y1_hi[ysl][arow][k0];
        ax_lo = *(const s16x8*)&g_y1_lo[ysl][arow][k0];
      }
#pragma unroll
      for (int n2 = 0; n2 < 3; ++n2) {
        const int c = n2 * 16 + lrow;
        const int boff = (c << 8) + ((((kk << 2) + kg) ^ (c & 7)) << 3);
        s16x8 bh_hi = *(const s16x8*)&L_whh_hi[boff];
        s16x8 bh_lo = *(const s16x8*)&L_whh_lo[boff];
        agh[n2] = MFMA16(ah_hi, bh_hi, agh[n2], 0, 0, 0);
        agh[n2] = MFMA16(ah_hi, bh_lo, agh[n2], 0, 0, 0);
        agh[n2] = MFMA16(ah_lo, bh_hi, agh[n2], 0, 0, 0);
        s16x8 bx_hi = *(const s16x8*)&L_wih_hi[boff];
        s16x8 bx_lo = *(const s16x8*)&L_wih_lo[boff];
        agx[n2] = MFMA16(ax_hi, bx_hi, agx[n2], 0, 0, 0);
        agx[n2] = MFMA16(ax_hi, bx_lo, agx[n2], 0, 0, 0);
        agx[n2] = MFMA16(ax_lo, bx_hi, agx[n2], 0, 0, 0);
      }
    }

    // ===== gates + h update (D layout: row = 4*kg + j, col = lrow; m89-verified)
#pragma unroll
    for (int j = 0; j < 4; ++j) {
      const int brow = rowbase + 4 * kg + j;
      float r = 1.f / (1.f + expf(-(agx[0][j] + agh[0][j] + b_r)));
      float z = 1.f / (1.f + expf(-(agx[1][j] + agh[1][j] + b_z)));
      float n = tanhf(agx[2][j] + bi_n + r * (agh[2][j] + bh_n));
      float hp = bf2f(g_h_hi[s][pb][brow][hcol]) + bf2f(g_h_lo[s][pb][brow][hcol]);
      float hn = (1.f - z) * n + z * hp;
      unsigned short hh = f2bf(hn);
      g_h_hi[s][cb][brow][hcol] = hh;
      g_h_lo[s][cb][brow][hcol] = f2bf(hn - bf2f(hh));
    }

    ENG_BARRIER(t + 2);   // publish h_new within the engine group

    // designated wg clears its group's y1 flags (all group reads done pre-barrier)
    if (s < 2 && i == 0 && tid < 16) flag_st(&g_y1f[s][q][ysl][tid], 0u);

    // ===== output projection: ao = h_new(full K) @ Wout_slice^T
    f32x4 ao = (f32x4){0.f, 0.f, 0.f, 0.f};
    const unsigned short* __restrict__ hc_hi = &g_h_hi[s][cb][0][0];
    const unsigned short* __restrict__ hc_lo = &g_h_lo[s][cb][0][0];
    for (int kk = 0; kk < 8; ++kk) {
      const int k0 = kk * 32 + kg * 8;
      s16x8 a_hi = *(const s16x8*)&hc_hi[arow * NHID + k0];
      s16x8 a_lo = *(const s16x8*)&hc_lo[arow * NHID + k0];
      const int c = lrow;
      const int boff = (c << 8) + ((((kk << 2) + kg) ^ (c & 7)) << 3);
      s16x8 b_hi = *(const s16x8*)&L_wo_hi[boff];
      s16x8 b_lo = *(const s16x8*)&L_wo_lo[boff];
      ao = MFMA16(a_hi, b_hi, ao, 0, 0, 0);
      ao = MFMA16(a_hi, b_lo, ao, 0, 0, 0);
      ao = MFMA16(a_lo, b_hi, ao, 0, 0, 0);
    }

    // ===== engine tails
    if (s == 2) {                       // publish s2x2
      if (tid == 0) spin2(&g_s2f[q][i], 0u, 0u, sdp);   // WAR: slot free
      __syncthreads();
#pragma unroll
      for (int j = 0; j < 4; ++j) {
        const int brow = rowbase + 4 * kg + j;
        g_s2[brow][hcol] = ao[j] + b_o;
      }
      __syncthreads();
      if (tid == 0) { fence_rel(); flag_st(&g_s2f[q][i], (unsigned)(t + 1)); }
    } else if (s == 3) {                // y1 = e(s2x2)*x1 + t2x2
      if (tid == 0) spin2(&g_s2f[q][i], (unsigned)(t + 1), (unsigned)(t + 1), sdp);
      if (tid == 1) spin2(&g_y1f[0][q][ysl][i], 0u, 0u, sdp);   // ring WAR
      if (tid == 2) spin2(&g_y1f[1][q][ysl][i], 0u, 0u, sdp);
      if (tid == 0) fence_acq();        // s2 data
      __syncthreads();
#pragma unroll
      for (int j = 0; j < 4; ++j) {
        const int brow = rowbase + 4 * kg + j;
        float t2 = ao[j] + b_o;
        float s2v = g_s2[brow][hcol];
        float x1v = x[((size_t)brow * NTIME + t) * NDIM + hcol];
        float y1 = expf(ESC * atanf(s2v)) * x1v + t2;
        out[((size_t)brow * NTIME + t) * NDIM + hcol] = y1;
        unsigned short hh = f2bf(y1);
        g_y1_hi[ysl][brow][hcol] = hh;
        g_y1_lo[ysl][brow][hcol] = f2bf(y1 - bf2f(hh));
      }
      __syncthreads();
      if (tid == 0) {
        flag_st(&g_s2f[q][i], 0u);      // consumed (reads drained by barrier)
        fence_rel();
        flag_st(&g_y1f[0][q][ysl][i], (unsigned)(t + 1));
        flag_st(&g_y1f[1][q][ysl][i], (unsigned)(t + 1));
      }
    } else if (s == 0) {                // publish s1y1
      if (tid == 0) spin2(&g_s1f[t & 1][q][i], 0u, 0u, sdp);   // WAR
      __syncthreads();
#pragma unroll
      for (int j = 0; j < 4; ++j) {
        const int brow = rowbase + 4 * kg + j;
        g_s1[t & 1][brow][hcol] = ao[j] + b_o;
      }
      __syncthreads();
      if (tid == 0) { fence_rel(); flag_st(&g_s1f[t & 1][q][i], (unsigned)(t + 1)); }
    } else {                            // s == 1: y2 = e(s1y1)*x2 + t1y1
      if (tid == 0) spin2(&g_s1f[t & 1][q][i], (unsigned)(t + 1), (unsigned)(t + 1), sdp);
      if (tid == 0) fence_acq();        // s1 data
      __syncthreads();
#pragma unroll
      for (int j = 0; j < 4; ++j) {
        const int brow = rowbase + 4 * kg + j;
        float t1 = ao[j] + b_o;
        float s1v = g_s1[t & 1][brow][hcol];
        float x2v = x[((size_t)brow * NTIME + t) * NDIM + NHID + hcol];
        out[((size_t)brow * NTIME + t) * NDIM + NHID + hcol] =
            expf(ESC * atanf(s1v)) * x2v + t1;
      }
      __syncthreads();
      if (tid == 0) flag_st(&g_s1f[t & 1][q][i], 0u);   // consumed
    }
  }
#undef ENG_BARRIER
}

extern "C" void kernel_launch(void* const* d_in, const int* in_sizes, int n_in,
                              void* d_out, int out_size, void* d_ws, size_t ws_size,
                              hipStream_t stream) {
  (void)in_sizes; (void)n_in; (void)out_size; (void)d_ws; (void)ws_size;
  const float* x    = (const float*)d_in[0];
  const float* Wih  = (const float*)d_in[1];
  const float* Whh  = (const float*)d_in[2];
  const float* bih  = (const float*)d_in[3];
  const float* bhh  = (const float*)d_in[4];
  const float* Wout = (const float*)d_in[5];
  const float* bout = (const float*)d_in[6];
  float* out = (float*)d_out;

  hipLaunchKernelGGL(revgru, dim3(256), dim3(256), 0, stream,
                     x, Wih, Whh, bih, bhh, Wout, bout, out);
}